// Round 6
// baseline (236.726 us; speedup 1.0000x reference)
//
#include <hip/hip_runtime.h>
#include <stdint.h>

#define TT 12
#define NN 325
#define HH 64
#define EE 32
#define LHH 128
#define OO 12
#define CIN 97
#define MOFF 65
#define BB 64

typedef __attribute__((ext_vector_type(8))) short bf8;
typedef __attribute__((ext_vector_type(4))) float f4;
typedef __attribute__((ext_vector_type(2))) float f2;

__device__ __forceinline__ float sigf(float x) {
  return __builtin_amdgcn_rcpf(1.f + __builtin_amdgcn_exp2f(-1.4426950408889634f * x));
}
__device__ __forceinline__ float tanhfast(float x) {
  // tanh(x) = 1 - 2/(1+e^{2x});  e^{2x} = 2^{2x*log2e}
  return 1.f - 2.f * __builtin_amdgcn_rcpf(1.f + __builtin_amdgcn_exp2f(2.8853900817779268f * x));
}
__device__ __forceinline__ unsigned short f2bf(float f) {  // RNE float->bf16
  unsigned int u = __float_as_uint(f);
  u += 0x7fffu + ((u >> 16) & 1u);
  return (unsigned short)(u >> 16);
}
__device__ __forceinline__ float bf2f(unsigned short s) {
  return __uint_as_float(((unsigned int)s) << 16);
}

// ---------------------------------------------------------------------------
// k_prep: ONE kernel, grid 1040, zero cross-block dependencies.
//  Every block recomputes meta for its 16 batches (L2-hot lines).
//  Blocks 0..1023 (g, i=col-slice, bq=batch-quarter): gate-g lwh hidden for
//    16 batches (8 dots/thread) then 16x64 GEMM over K=128 with W2 read
//    directly from L2 (float2), storing bf16 Wh in MFMA B-frag order.
//  Blocks 1024..1039 (g, bq): lwx + lb MLPs -> wx_ws / bg_ws.
// ---------------------------------------------------------------------------
__global__ __launch_bounds__(256) void k_prep(
    const float* __restrict__ x,
    const float* __restrict__ xw1, const float* __restrict__ xb1,
    const float* __restrict__ xw2, const float* __restrict__ xb2,
    const float* __restrict__ hw1, const float* __restrict__ hb1,
    const float* __restrict__ hw2, const float* __restrict__ hb2,
    const float* __restrict__ bw1, const float* __restrict__ bb1,
    const float* __restrict__ bw2, const float* __restrict__ bb2,
    unsigned short* __restrict__ whb,
    float* __restrict__ wx_ws, float* __restrict__ bg_ws)
{
  const int bi = blockIdx.x, tid = threadIdx.x;
  const bool gemm = (bi < 1024);
  const int g  = gemm ? (bi >> 8) : ((bi - 1024) >> 2);
  const int bq = gemm ? (bi & 3) : ((bi - 1024) & 3);

  __shared__ float meta_s[16][EE];            // 2 KB
  __shared__ float hbuf[2][16][132];          // 16.9 KB (GEMM uses [0] only)

  // meta for this block's 16 batches: 512 (b,e) pairs, 2/thread, 12 loads each
  for (int p = tid; p < 512; p += 256) {
    const int bl = p >> 5, e = p & 31;
    const int b = bq * 16 + bl;
    float s = 0.f;
    #pragma unroll
    for (int t = 0; t < TT; ++t)
      s += x[(size_t)((b * TT + t) * NN) * CIN + MOFF + e];
    meta_s[bl][e] = s * (1.f / 12.f);
  }
  __syncthreads();

  if (gemm) {
    const int i = (bi >> 2) & 63;
    // lwh hidden for gate g, 16 batches: 2048 dots of 32 (8/thread)
    for (int m = tid; m < 16 * LHH; m += 256) {
      const int bl = m >> 7, l = m & 127;
      float a = hb1[g * LHH + l];
      const float* w = hw1 + (size_t)g * (EE * LHH) + l;
      #pragma unroll
      for (int e = 0; e < EE; ++e) a = fmaf(meta_s[bl][e], w[e * LHH], a);
      hbuf[0][bl][l] = fmaxf(a, 0.f);
    }
    __syncthreads();

    // GEMM 16x64 over K=128; W2 straight from L2 (float2 per K-row)
    const int r0 = (tid >> 5) * 2, j0 = (tid & 31) * 2;
    const float* w2p = hw2 + (size_t)(g * LHH) * 4096 + i * 64 + j0;
    float acc[2][2] = {};
    for (int l = 0; l < LHH; l += 4) {
      const f4 h0 = *(const f4*)&hbuf[0][r0][l];
      const f4 h1 = *(const f4*)&hbuf[0][r0 + 1][l];
      #pragma unroll
      for (int ll = 0; ll < 4; ++ll) {
        const f2 wv = *(const f2*)(w2p + (size_t)(l + ll) * 4096);
        acc[0][0] = fmaf(h0[ll], wv[0], acc[0][0]);
        acc[0][1] = fmaf(h0[ll], wv[1], acc[0][1]);
        acc[1][0] = fmaf(h1[ll], wv[0], acc[1][0]);
        acc[1][1] = fmaf(h1[ll], wv[1], acc[1][1]);
      }
    }

    // store bf16 in MFMA B-frag order (formula identical to R1-R5)
    const int kh = i >> 5, quad = (i >> 3) & 3, j8 = i & 7;
    #pragma unroll
    for (int rr = 0; rr < 2; ++rr) {
      const int b = bq * 16 + r0 + rr;
      #pragma unroll
      for (int jj = 0; jj < 2; ++jj) {
        const int j = j0 + jj;
        const float v = acc[rr][jj] + hb2[g * 4096 + i * 64 + j];
        const int col = g * 64 + j;
        const int nt = col >> 4, c16 = col & 15;
        const int lane = quad * 16 + c16;
        whb[(size_t)((b * 32 + kh * 16 + nt) * 64 + lane) * 8 + j8] = f2bf(v);
      }
    }
  } else {
    // lwx (mlp 0) + lb (mlp 1) hiddens: 4096 dots of 32 (16/thread)
    for (int m = tid; m < 2 * 16 * LHH; m += 256) {
      const int mlp = m >> 11, rem = m & 2047, bl = rem >> 7, l = rem & 127;
      const float* W1 = mlp ? bw1 : xw1;
      const float* B1 = mlp ? bb1 : xb1;
      float a = B1[g * LHH + l];
      const float* w = W1 + (size_t)g * (EE * LHH) + l;
      #pragma unroll
      for (int e = 0; e < EE; ++e) a = fmaf(meta_s[bl][e], w[e * LHH], a);
      hbuf[mlp][bl][l] = fmaxf(a, 0.f);
    }
    __syncthreads();

    // outputs: thread (h = tid&63, bl0 = (tid>>6)*4) does 4 batches x 2 dsts
    const int h = tid & 63, bl0 = (tid >> 6) * 4;
    const float* wxp = xw2 + (size_t)g * (LHH * HH) + h;
    const float* wbp = bw2 + (size_t)g * (LHH * HH) + h;
    float accx[4], accb[4];
    #pragma unroll
    for (int k = 0; k < 4; ++k) {
      accx[k] = xb2[g * HH + h];
      accb[k] = bb2[g * HH + h];
    }
    for (int l = 0; l < LHH; ++l) {
      const float wxl = wxp[l * HH], wbl = wbp[l * HH];
      #pragma unroll
      for (int k = 0; k < 4; ++k) {
        accx[k] = fmaf(hbuf[0][bl0 + k][l], wxl, accx[k]);
        accb[k] = fmaf(hbuf[1][bl0 + k][l], wbl, accb[k]);
      }
    }
    #pragma unroll
    for (int k = 0; k < 4; ++k) {
      const int b = bq * 16 + bl0 + k;
      wx_ws[b * 256 + g * 64 + h] = accx[k];
      bg_ws[b * 256 + g * 64 + h] = accb[k];
    }
  }
}

// ---------------------------------------------------------------------------
// Kernel 3 (T-loop byte-identical to R4/R5): grid (11 x 32-row tiles, 64 b).
// Staging now reads the x signal directly (xg buffer + dependency deleted).
// ---------------------------------------------------------------------------
__global__ __launch_bounds__(256, 3) void k_lstm(
    const float* __restrict__ x, const float* __restrict__ wx_ws,
    const float* __restrict__ bg_ws, const unsigned short* __restrict__ whb,
    const float* __restrict__ fc1W, const float* __restrict__ fc1b,
    const float* __restrict__ fc2W, const float* __restrict__ fc2b,
    float* __restrict__ out)
{
  const int rb = blockIdx.x, b = blockIdx.y, tid = threadIdx.x;
  const int wave = tid >> 6, lane = tid & 63, quad = lane >> 4, c16 = lane & 15;
  const int n0 = rb * 32;

  __shared__ __align__(16) unsigned short Hs[2][2][16][72];  // [buf][tile][row][col]
  __shared__ float Xs[TT][32];
  __shared__ float fc1s[HH * 32];
  __shared__ float fc2s[32 * OO];
  __shared__ float HIDs[32][36];
  __shared__ float fc1bs[32];
  __shared__ float fc2bs[OO];

  for (int idx = tid; idx < TT * 32; idx += 256) {
    const int t = idx >> 5, r = idx & 31, n = n0 + r;
    Xs[t][r] = (n < NN) ? x[(size_t)((b * TT + t) * NN + n) * CIN] : 0.f;
  }
  for (int idx = tid; idx < HH * 32; idx += 256) fc1s[idx] = fc1W[idx];
  for (int idx = tid; idx < 32 * OO; idx += 256) fc2s[idx] = fc2W[idx];
  if (tid < 32) fc1bs[tid] = fc1b[tid];
  if (tid < OO) fc2bs[tid] = fc2b[tid];

  float wxv[4], bgv[4];
  #pragma unroll
  for (int g = 0; g < 4; ++g) {
    wxv[g] = wx_ws[b * 256 + g * 64 + wave * 16 + c16];
    bgv[g] = bg_ws[b * 256 + g * 64 + wave * 16 + c16];
  }
  bf8 wf[2][4];
  #pragma unroll
  for (int kh = 0; kh < 2; ++kh)
    #pragma unroll
    for (int g = 0; g < 4; ++g)
      wf[kh][g] = *(const bf8*)(whb + (size_t)((b * 32 + kh * 16 + g * 4 + wave) * 64 + lane) * 8);

  float cst[2][4];
  #pragma unroll
  for (int ta = 0; ta < 2; ++ta)
    #pragma unroll
    for (int r = 0; r < 4; ++r) cst[ta][r] = 0.f;

  __syncthreads();

  #pragma unroll 1
  for (int t = 0; t < TT; ++t) {
    bf8 af[2][2];
    if (t > 0) {
      #pragma unroll
      for (int ta = 0; ta < 2; ++ta) {
        af[ta][0] = *(const bf8*)&Hs[(t - 1) & 1][ta][c16][quad * 8];
        af[ta][1] = *(const bf8*)&Hs[(t - 1) & 1][ta][c16][32 + quad * 8];
      }
    }
    f4 ac[2][4];
    #pragma unroll
    for (int ta = 0; ta < 2; ++ta) {
      float xr[4];
      #pragma unroll
      for (int r = 0; r < 4; ++r) xr[r] = Xs[t][ta * 16 + quad * 4 + r];
      #pragma unroll
      for (int g = 0; g < 4; ++g)
        #pragma unroll
        for (int r = 0; r < 4; ++r)
          ac[ta][g][r] = fmaf(xr[r], wxv[g], bgv[g]);
    }
    if (t > 0) {
      #pragma unroll
      for (int ta = 0; ta < 2; ++ta)
        #pragma unroll
        for (int g = 0; g < 4; ++g) {
          ac[ta][g] = __builtin_amdgcn_mfma_f32_16x16x32_bf16(af[ta][0], wf[0][g], ac[ta][g], 0, 0, 0);
          ac[ta][g] = __builtin_amdgcn_mfma_f32_16x16x32_bf16(af[ta][1], wf[1][g], ac[ta][g], 0, 0, 0);
        }
    }
    #pragma unroll
    for (int ta = 0; ta < 2; ++ta)
      #pragma unroll
      for (int r = 0; r < 4; ++r) {
        const float gg = tanhfast(ac[ta][0][r]);
        const float ii = sigf(ac[ta][1][r]);
        const float ff = sigf(ac[ta][2][r]);
        const float oo = sigf(ac[ta][3][r]);
        const float cc = fmaf(gg, ii, cst[ta][r] * ff);
        cst[ta][r] = cc;
        const float hh = tanhfast(cc) * oo;
        Hs[t & 1][ta][quad * 4 + r][wave * 16 + c16] = f2bf(hh);
      }
    __syncthreads();
  }

  // ---- head, fp32. final h is in Hs[1]. ----
  {
    const int row32 = tid & 31, uu = tid >> 5;
    const int ta = row32 >> 4, row = row32 & 15;
    float hacc[4];
    #pragma unroll
    for (int j = 0; j < 4; ++j) hacc[j] = fc1bs[uu * 4 + j];
    #pragma unroll
    for (int kc = 0; kc < 8; ++kc) {
      const bf8 hv = *(const bf8*)&Hs[1][ta][row][kc * 8];
      #pragma unroll
      for (int j8 = 0; j8 < 8; ++j8) {
        const float hk = fmaxf(bf2f((unsigned short)hv[j8]), 0.f);  // relu(h)
        const int k = kc * 8 + j8;
        #pragma unroll
        for (int j = 0; j < 4; ++j)
          hacc[j] = fmaf(hk, fc1s[k * 32 + uu * 4 + j], hacc[j]);
      }
    }
    #pragma unroll
    for (int j = 0; j < 4; ++j)
      HIDs[row32][uu * 4 + j] = fmaxf(hacc[j], 0.f);
  }
  __syncthreads();
  for (int idx = tid; idx < 32 * OO; idx += 256) {
    const int o = idx >> 5, row32 = idx & 31;
    float a = fc2bs[o];
    #pragma unroll
    for (int k = 0; k < 32; ++k)
      a = fmaf(HIDs[row32][k], fc2s[k * OO + o], a);
    const int n = n0 + row32;
    if (n < NN)
      out[b * (OO * NN) + o * NN + n] = a;
  }
}

// ---------------------------------------------------------------------------
extern "C" void kernel_launch(void* const* d_in, const int* in_sizes, int n_in,
                              void* d_out, int out_size, void* d_ws, size_t ws_size,
                              hipStream_t stream) {
  const float* x    = (const float*)d_in[0];
  const float* xw1  = (const float*)d_in[1];
  const float* xb1  = (const float*)d_in[2];
  const float* xw2  = (const float*)d_in[3];
  const float* xb2  = (const float*)d_in[4];
  const float* hw1  = (const float*)d_in[5];
  const float* hb1  = (const float*)d_in[6];
  const float* hw2  = (const float*)d_in[7];
  const float* hb2  = (const float*)d_in[8];
  const float* bw1  = (const float*)d_in[9];
  const float* bb1  = (const float*)d_in[10];
  const float* bw2  = (const float*)d_in[11];
  const float* bb2  = (const float*)d_in[12];
  const float* fc1W = (const float*)d_in[13];
  const float* fc1b = (const float*)d_in[14];
  const float* fc2W = (const float*)d_in[15];
  const float* fc2b = (const float*)d_in[16];
  float* out = (float*)d_out;

  float* ws = (float*)d_ws;
  float* wx_ws = ws;                         // [64][256] = 16384 floats
  float* bg_ws = ws + 16384;                 // [64][256] = 16384
  unsigned short* whb = (unsigned short*)(ws + 32768);  // 1048576 u16

  k_prep<<<1040, 256, 0, stream>>>(x, xw1, xb1, xw2, xb2, hw1, hb1, hw2, hb2,
                                   bw1, bb1, bw2, bb2, whb, wx_ws, bg_ws);
  k_lstm<<<dim3(11, 64), 256, 0, stream>>>(x, wx_ws, bg_ws, whb,
                                           fc1W, fc1b, fc2W, fc2b, out);
}

// Round 7
// 232.084 us; speedup vs baseline: 1.0200x; 1.0200x over previous
//
#include <hip/hip_runtime.h>
#include <stdint.h>

#define TT 12
#define NN 325
#define HH 64
#define EE 32
#define LHH 128
#define OO 12
#define CIN 97
#define MOFF 65
#define BB 64

typedef __attribute__((ext_vector_type(8))) short bf8;
typedef __attribute__((ext_vector_type(4))) float f4;
typedef __attribute__((ext_vector_type(2))) float f2;

__device__ __forceinline__ float sigf(float x) {
  return __builtin_amdgcn_rcpf(1.f + __builtin_amdgcn_exp2f(-1.4426950408889634f * x));
}
__device__ __forceinline__ float tanhfast(float x) {
  return 1.f - 2.f * __builtin_amdgcn_rcpf(1.f + __builtin_amdgcn_exp2f(2.8853900817779268f * x));
}
__device__ __forceinline__ unsigned short f2bf(float f) {  // RNE float->bf16
  unsigned int u = __float_as_uint(f);
  u += 0x7fffu + ((u >> 16) & 1u);
  return (unsigned short)(u >> 16);
}
__device__ __forceinline__ float bf2f(unsigned short s) {
  return __uint_as_float(((unsigned int)s) << 16);
}

// ---------------------------------------------------------------------------
// k_meta0: grid 64. ONLY the meta mean -> meta_ws[64][32] (8 KB, L2-hot for
// k_main). (t,e)-parallel staging, 32-lane reduce. ~3 us incl. launch.
// ---------------------------------------------------------------------------
__global__ __launch_bounds__(256) void k_meta0(
    const float* __restrict__ x, float* __restrict__ meta_ws)
{
  const int b = blockIdx.x, tid = threadIdx.x;
  __shared__ float mpart[TT][EE];
  for (int idx = tid; idx < TT * EE; idx += 256) {
    const int t = idx >> 5, e = idx & 31;
    mpart[t][e] = x[(size_t)((b * TT + t) * NN) * CIN + MOFF + e];
  }
  __syncthreads();
  if (tid < EE) {
    float s = 0.f;
    #pragma unroll
    for (int t = 0; t < TT; ++t) s += mpart[t][tid];
    meta_ws[b * EE + tid] = s * (1.f / 12.f);
  }
}

// ---------------------------------------------------------------------------
// k_main: grid 1040, ONE launch, no cross-block deps (meta comes from the
// 8 KB meta_ws, NOT recomputed from x -- the R3/R6 poison).
//  Blocks 0..1023 (g,i,bq): gate-g lwh hidden for 16 batches (8 dots/thread
//    from LDS meta), GEMM 16x64 over K=128 with W2 staged COALESCED into LDS
//    in two 16 KB K-chunks (27 KB LDS total -> 4 blocks/CU), bf16 Wh out in
//    MFMA B-frag order; x-signal gather spread across these blocks.
//  Blocks 1024..1039 (g,bq): lwx + lb MLPs -> wx_ws / bg_ws.
// ---------------------------------------------------------------------------
__global__ __launch_bounds__(256, 4) void k_main(
    const float* __restrict__ x, const float* __restrict__ meta_ws,
    const float* __restrict__ xw1, const float* __restrict__ xb1,
    const float* __restrict__ xw2, const float* __restrict__ xb2,
    const float* __restrict__ hw1, const float* __restrict__ hb1,
    const float* __restrict__ hw2, const float* __restrict__ hb2,
    const float* __restrict__ bw1, const float* __restrict__ bb1,
    const float* __restrict__ bw2, const float* __restrict__ bb2,
    unsigned short* __restrict__ whb, float* __restrict__ xg,
    float* __restrict__ wx_ws, float* __restrict__ bg_ws)
{
  const int bi = blockIdx.x, tid = threadIdx.x;
  const bool gemm = (bi < 1024);
  const int g  = gemm ? (bi >> 8) : ((bi - 1024) >> 2);
  const int bq = gemm ? (bi & 3) : ((bi - 1024) & 3);

  __shared__ float meta_s[16][EE];     // 2 KB
  __shared__ float hbuf[2][16][132];   // 16.9 KB (GEMM uses [0] only)
  __shared__ float w2s[64][64];        // 16 KB K-chunk of W2

  // meta for this block's 16 batches from the tiny ws (coalesced, L2-hot)
  for (int p = tid; p < 16 * EE; p += 256)
    meta_s[p >> 5][p & 31] = meta_ws[(bq * 16 + (p >> 5)) * EE + (p & 31)];
  __syncthreads();

  if (gemm) {
    const int i = (bi >> 2) & 63;

    // x-signal gather: 249600 / 1024 blocks = 244 (1 per thread)
    {
      const int flat = bi * 244 + tid;
      if (tid < 244 && flat < BB * TT * NN) {
        const int b = flat / (TT * NN);
        const int r = flat - b * (TT * NN);
        const int t = r / NN;
        const int n = r - t * NN;
        xg[flat] = x[(size_t)((b * TT + t) * NN + n) * CIN];
      }
    }

    // lwh hidden for gate g, 16 batches (8 dots of 32 per thread)
    for (int m = tid; m < 16 * LHH; m += 256) {
      const int bl = m >> 7, l = m & 127;
      float a = hb1[g * LHH + l];
      const float* w = hw1 + (size_t)g * (EE * LHH) + l;
      #pragma unroll
      for (int e = 0; e < EE; ++e) a = fmaf(meta_s[bl][e], w[e * LHH], a);
      hbuf[0][bl][l] = fmaxf(a, 0.f);
    }

    // GEMM 16x64 over K=128, W2 staged coalesced in two 64-row chunks
    const int r0 = (tid >> 5) * 2, j0 = (tid & 31) * 2;
    float acc[2][2] = {};
    #pragma unroll
    for (int half = 0; half < 2; ++half) {
      __syncthreads();  // (1st: hbuf+meta ready; 2nd: prev chunk consumed)
      for (int idx = tid; idx < 64 * 64; idx += 256)
        w2s[idx >> 6][idx & 63] =
            hw2[(size_t)(g * LHH + half * 64 + (idx >> 6)) * 4096 + i * 64 + (idx & 63)];
      __syncthreads();
      for (int l = 0; l < 64; l += 4) {
        const f4 h0 = *(const f4*)&hbuf[0][r0][half * 64 + l];
        const f4 h1 = *(const f4*)&hbuf[0][r0 + 1][half * 64 + l];
        #pragma unroll
        for (int ll = 0; ll < 4; ++ll) {
          const f2 wv = *(const f2*)&w2s[l + ll][j0];
          acc[0][0] = fmaf(h0[ll], wv[0], acc[0][0]);
          acc[0][1] = fmaf(h0[ll], wv[1], acc[0][1]);
          acc[1][0] = fmaf(h1[ll], wv[0], acc[1][0]);
          acc[1][1] = fmaf(h1[ll], wv[1], acc[1][1]);
        }
      }
    }

    // store bf16 in MFMA B-frag order (formula identical to R1-R6)
    const int kh = i >> 5, quad = (i >> 3) & 3, j8 = i & 7;
    #pragma unroll
    for (int rr = 0; rr < 2; ++rr) {
      const int b = bq * 16 + r0 + rr;
      #pragma unroll
      for (int jj = 0; jj < 2; ++jj) {
        const int j = j0 + jj;
        const float v = acc[rr][jj] + hb2[g * 4096 + i * 64 + j];
        const int col = g * 64 + j;
        const int nt = col >> 4, c16 = col & 15;
        const int lane = quad * 16 + c16;
        whb[(size_t)((b * 32 + kh * 16 + nt) * 64 + lane) * 8 + j8] = f2bf(v);
      }
    }
  } else {
    // lwx (mlp 0) + lb (mlp 1) hiddens: 16 dots of 32 per thread
    for (int m = tid; m < 2 * 16 * LHH; m += 256) {
      const int mlp = m >> 11, rem = m & 2047, bl = rem >> 7, l = rem & 127;
      const float* W1 = mlp ? bw1 : xw1;
      const float* B1 = mlp ? bb1 : xb1;
      float a = B1[g * LHH + l];
      const float* w = W1 + (size_t)g * (EE * LHH) + l;
      #pragma unroll
      for (int e = 0; e < EE; ++e) a = fmaf(meta_s[bl][e], w[e * LHH], a);
      hbuf[mlp][bl][l] = fmaxf(a, 0.f);
    }
    __syncthreads();

    // outputs: thread (h = tid&63, bl0 = (tid>>6)*4): 4 batches x 2 dsts
    const int h = tid & 63, bl0 = (tid >> 6) * 4;
    const float* wxp = xw2 + (size_t)g * (LHH * HH) + h;
    const float* wbp = bw2 + (size_t)g * (LHH * HH) + h;
    float accx[4], accb[4];
    #pragma unroll
    for (int k = 0; k < 4; ++k) {
      accx[k] = xb2[g * HH + h];
      accb[k] = bb2[g * HH + h];
    }
    for (int l = 0; l < LHH; ++l) {
      const float wxl = wxp[l * HH], wbl = wbp[l * HH];
      #pragma unroll
      for (int k = 0; k < 4; ++k) {
        accx[k] = fmaf(hbuf[0][bl0 + k][l], wxl, accx[k]);
        accb[k] = fmaf(hbuf[1][bl0 + k][l], wbl, accb[k]);
      }
    }
    #pragma unroll
    for (int k = 0; k < 4; ++k) {
      const int b = bq * 16 + bl0 + k;
      wx_ws[b * 256 + g * 64 + h] = accx[k];
      bg_ws[b * 256 + g * 64 + h] = accb[k];
    }
  }
}

// ---------------------------------------------------------------------------
// Kernel 3 (byte-identical to R5): grid (11 x 32-row tiles, 64 batches).
// ---------------------------------------------------------------------------
__global__ __launch_bounds__(256, 3) void k_lstm(
    const float* __restrict__ xg, const float* __restrict__ wx_ws,
    const float* __restrict__ bg_ws, const unsigned short* __restrict__ whb,
    const float* __restrict__ fc1W, const float* __restrict__ fc1b,
    const float* __restrict__ fc2W, const float* __restrict__ fc2b,
    float* __restrict__ out)
{
  const int rb = blockIdx.x, b = blockIdx.y, tid = threadIdx.x;
  const int wave = tid >> 6, lane = tid & 63, quad = lane >> 4, c16 = lane & 15;
  const int n0 = rb * 32;

  __shared__ __align__(16) unsigned short Hs[2][2][16][72];  // [buf][tile][row][col]
  __shared__ float Xs[TT][32];
  __shared__ float fc1s[HH * 32];
  __shared__ float fc2s[32 * OO];
  __shared__ float HIDs[32][36];
  __shared__ float fc1bs[32];
  __shared__ float fc2bs[OO];

  for (int idx = tid; idx < TT * 32; idx += 256) {
    const int t = idx >> 5, r = idx & 31, n = n0 + r;
    Xs[t][r] = (n < NN) ? xg[b * (TT * NN) + t * NN + n] : 0.f;
  }
  for (int idx = tid; idx < HH * 32; idx += 256) fc1s[idx] = fc1W[idx];
  for (int idx = tid; idx < 32 * OO; idx += 256) fc2s[idx] = fc2W[idx];
  if (tid < 32) fc1bs[tid] = fc1b[tid];
  if (tid < OO) fc2bs[tid] = fc2b[tid];

  float wxv[4], bgv[4];
  #pragma unroll
  for (int g = 0; g < 4; ++g) {
    wxv[g] = wx_ws[b * 256 + g * 64 + wave * 16 + c16];
    bgv[g] = bg_ws[b * 256 + g * 64 + wave * 16 + c16];
  }
  bf8 wf[2][4];
  #pragma unroll
  for (int kh = 0; kh < 2; ++kh)
    #pragma unroll
    for (int g = 0; g < 4; ++g)
      wf[kh][g] = *(const bf8*)(whb + (size_t)((b * 32 + kh * 16 + g * 4 + wave) * 64 + lane) * 8);

  float cst[2][4];
  #pragma unroll
  for (int ta = 0; ta < 2; ++ta)
    #pragma unroll
    for (int r = 0; r < 4; ++r) cst[ta][r] = 0.f;

  __syncthreads();

  #pragma unroll 1
  for (int t = 0; t < TT; ++t) {
    bf8 af[2][2];
    if (t > 0) {
      #pragma unroll
      for (int ta = 0; ta < 2; ++ta) {
        af[ta][0] = *(const bf8*)&Hs[(t - 1) & 1][ta][c16][quad * 8];
        af[ta][1] = *(const bf8*)&Hs[(t - 1) & 1][ta][c16][32 + quad * 8];
      }
    }
    f4 ac[2][4];
    #pragma unroll
    for (int ta = 0; ta < 2; ++ta) {
      float xr[4];
      #pragma unroll
      for (int r = 0; r < 4; ++r) xr[r] = Xs[t][ta * 16 + quad * 4 + r];
      #pragma unroll
      for (int g = 0; g < 4; ++g)
        #pragma unroll
        for (int r = 0; r < 4; ++r)
          ac[ta][g][r] = fmaf(xr[r], wxv[g], bgv[g]);
    }
    if (t > 0) {
      #pragma unroll
      for (int ta = 0; ta < 2; ++ta)
        #pragma unroll
        for (int g = 0; g < 4; ++g) {
          ac[ta][g] = __builtin_amdgcn_mfma_f32_16x16x32_bf16(af[ta][0], wf[0][g], ac[ta][g], 0, 0, 0);
          ac[ta][g] = __builtin_amdgcn_mfma_f32_16x16x32_bf16(af[ta][1], wf[1][g], ac[ta][g], 0, 0, 0);
        }
    }
    #pragma unroll
    for (int ta = 0; ta < 2; ++ta)
      #pragma unroll
      for (int r = 0; r < 4; ++r) {
        const float gg = tanhfast(ac[ta][0][r]);
        const float ii = sigf(ac[ta][1][r]);
        const float ff = sigf(ac[ta][2][r]);
        const float oo = sigf(ac[ta][3][r]);
        const float cc = fmaf(gg, ii, cst[ta][r] * ff);
        cst[ta][r] = cc;
        const float hh = tanhfast(cc) * oo;
        Hs[t & 1][ta][quad * 4 + r][wave * 16 + c16] = f2bf(hh);
      }
    __syncthreads();
  }

  // ---- head, fp32. final h is in Hs[1]. ----
  {
    const int row32 = tid & 31, uu = tid >> 5;
    const int ta = row32 >> 4, row = row32 & 15;
    float hacc[4];
    #pragma unroll
    for (int j = 0; j < 4; ++j) hacc[j] = fc1bs[uu * 4 + j];
    #pragma unroll
    for (int kc = 0; kc < 8; ++kc) {
      const bf8 hv = *(const bf8*)&Hs[1][ta][row][kc * 8];
      #pragma unroll
      for (int j8 = 0; j8 < 8; ++j8) {
        const float hk = fmaxf(bf2f((unsigned short)hv[j8]), 0.f);  // relu(h)
        const int k = kc * 8 + j8;
        #pragma unroll
        for (int j = 0; j < 4; ++j)
          hacc[j] = fmaf(hk, fc1s[k * 32 + uu * 4 + j], hacc[j]);
      }
    }
    #pragma unroll
    for (int j = 0; j < 4; ++j)
      HIDs[row32][uu * 4 + j] = fmaxf(hacc[j], 0.f);
  }
  __syncthreads();
  for (int idx = tid; idx < 32 * OO; idx += 256) {
    const int o = idx >> 5, row32 = idx & 31;
    float a = fc2bs[o];
    #pragma unroll
    for (int k = 0; k < 32; ++k)
      a = fmaf(HIDs[row32][k], fc2s[k * OO + o], a);
    const int n = n0 + row32;
    if (n < NN)
      out[b * (OO * NN) + o * NN + n] = a;
  }
}

// ---------------------------------------------------------------------------
extern "C" void kernel_launch(void* const* d_in, const int* in_sizes, int n_in,
                              void* d_out, int out_size, void* d_ws, size_t ws_size,
                              hipStream_t stream) {
  const float* x    = (const float*)d_in[0];
  const float* xw1  = (const float*)d_in[1];
  const float* xb1  = (const float*)d_in[2];
  const float* xw2  = (const float*)d_in[3];
  const float* xb2  = (const float*)d_in[4];
  const float* hw1  = (const float*)d_in[5];
  const float* hb1  = (const float*)d_in[6];
  const float* hw2  = (const float*)d_in[7];
  const float* hb2  = (const float*)d_in[8];
  const float* bw1  = (const float*)d_in[9];
  const float* bb1  = (const float*)d_in[10];
  const float* bw2  = (const float*)d_in[11];
  const float* bb2  = (const float*)d_in[12];
  const float* fc1W = (const float*)d_in[13];
  const float* fc1b = (const float*)d_in[14];
  const float* fc2W = (const float*)d_in[15];
  const float* fc2b = (const float*)d_in[16];
  float* out = (float*)d_out;

  float* ws = (float*)d_ws;
  float* meta_ws = ws;                       // [64][32]      = 2048 floats
  float* wx_ws   = ws + 2048;                // [64][256]     = 16384
  float* bg_ws   = ws + 18432;               // [64][256]     = 16384
  float* xg_ws   = ws + 34816;               // [64][12][325] = 249600
  unsigned short* whb = (unsigned short*)(ws + 34816 + BB * TT * NN);  // 1048576 u16

  k_meta0<<<64, 256, 0, stream>>>(x, meta_ws);
  k_main<<<1040, 256, 0, stream>>>(x, meta_ws, xw1, xb1, xw2, xb2, hw1, hb1,
                                   hw2, hb2, bw1, bb1, bw2, bb2, whb, xg_ws,
                                   wx_ws, bg_ws);
  k_lstm<<<dim3(11, 64), 256, 0, stream>>>(xg_ws, wx_ws, bg_ws, whb,
                                           fc1W, fc1b, fc2W, fc2b, out);
}